// Round 1
// baseline (2693.580 us; speedup 1.0000x reference)
//
#include <hip/hip_runtime.h>

#define NS 64
#define NV 16
#define NH 8
#define VROW 368   // 8 heads * 46

// ---------- K0: init segment-max to ordered(-inf) ----------
__global__ void k_init_amax(unsigned* __restrict__ amax, int n){
  int i = blockIdx.x*256 + threadIdx.x;
  if(i<n) amax[i] = 0x007FFFFFu;   // ordered encoding of -inf
}

// ---------- K1: node transforms ----------
__global__ __launch_bounds__(256) void k_node(
  const float* __restrict__ ni,
  const float* __restrict__ wss, const float* __restrict__ wsv,
  const float* __restrict__ wds, const float* __restrict__ wdv,
  float* __restrict__ xs_s, float* __restrict__ xs_d,
  float* __restrict__ xv_s, float* __restrict__ xv_d, int N)
{
  __shared__ float sW0[64*64], sW1[64*64];
  __shared__ float sV0[256], sV1[256];
  __shared__ float sRow[4][112];
  int t = threadIdx.x, wid = t>>6, lane = t&63;
  for(int i=t;i<4096;i+=256){ sW0[i]=wss[i]; sW1[i]=wds[i]; }
  if(t<256){ sV0[t]=wsv[t]; sV1[t]=wdv[t]; }
  __syncthreads();
  int node = blockIdx.x*4 + wid;
  if(node>=N) return;
  const float* row = ni + (size_t)node*112;
  if(lane<56) ((float2*)sRow[wid])[lane] = ((const float2*)row)[lane];
  float* r = sRow[wid];
  float a0=0.f, a1=0.f;
  #pragma unroll 8
  for(int k=0;k<64;k++){ float x=r[k]; a0+=x*sW0[k*64+lane]; a1+=x*sW1[k*64+lane]; }
  xs_s[(size_t)node*64+lane]=a0; xs_d[(size_t)node*64+lane]=a1;
  if(lane<48){
    int e_=lane/3, d_=lane-e_*3; float b0=0.f, b1=0.f;
    #pragma unroll
    for(int c=0;c<16;c++){ float x=r[64+c*3+d_]; b0+=x*sV0[c*16+e_]; b1+=x*sV1[c*16+e_]; }
    xv_s[(size_t)node*48+lane]=b0; xv_d[(size_t)node*48+lane]=b1;
  }
}

// ---------- K2: per-edge radial MLP + features + alpha ----------
struct WScr { float es[128]; float h[64]; float w[176]; float s[64]; float v[48]; float os[80]; };

__global__ __launch_bounds__(256) void k_edge(
  const int* __restrict__ esrc, const int* __restrict__ edst,
  const float* __restrict__ eattr, const float* __restrict__ escal,
  const float* __restrict__ w1, const float* __restrict__ b1,
  const float* __restrict__ w2, const float* __restrict__ b2,
  const float* __restrict__ adot,
  const float* __restrict__ xs_s, const float* __restrict__ xs_d,
  const float* __restrict__ xv_s, const float* __restrict__ xv_d,
  _Float16* __restrict__ value, float* __restrict__ alpha,
  unsigned* __restrict__ amax_u, int E)
{
  __shared__ float sW1[128*64];    // 32 KB, reused for 16 edges
  __shared__ WScr scr[4];
  int t = threadIdx.x, wid = t>>6, lane = t&63;
  for(int i=t;i<128*64;i+=256) sW1[i]=w1[i];
  __syncthreads();
  WScr& S = scr[wid];

  for(int it=0; it<4; ++it){
    int e = blockIdx.x*16 + it*4 + wid;
    if(e >= E) continue;
    // stage edge_scalars row
    const float* es = escal + (size_t)e*128;
    S.es[lane] = es[lane]; S.es[64+lane] = es[64+lane];
    // mid = es @ w1 + b1 (lane j computes mid[j])
    float acc = b1[lane];
    #pragma unroll 4
    for(int k=0;k<128;k++) acc += S.es[k]*sW1[k*64+lane];
    // LayerNorm across the wave, then silu
    float sum=acc, sq=acc*acc;
    #pragma unroll
    for(int o=32;o;o>>=1){ sum += __shfl_xor(sum,o); sq += __shfl_xor(sq,o); }
    float m = sum*(1.f/64.f);
    float var = sq*(1.f/64.f) - m*m;
    float xn = (acc-m)*rsqrtf(var+1e-5f);
    float h = xn/(1.f+expf(-xn));
    S.h[lane]=h;
    // w = h @ w2 + b2  (lane computes w[lane], w[64+lane], w[128+lane] if lane<48)
    float wa=b2[lane], wb=b2[64+lane], wc=(lane<48)?b2[128+lane]:0.f;
    for(int k=0;k<64;k++){
      float hk=S.h[k];
      wa += hk*w2[k*176+lane];
      wb += hk*w2[k*176+64+lane];
      if(lane<48) wc += hk*w2[k*176+128+lane];
    }
    S.w[lane]=wa; S.w[64+lane]=wb; if(lane<48) S.w[128+lane]=wc;
    // gather node features
    int si=esrc[e], di=edst[e];
    float sval = xs_s[(size_t)si*64+lane] + xs_d[(size_t)di*64+lane];
    S.s[lane]=sval;
    if(lane<48) S.v[lane] = xv_s[(size_t)si*48+lane] + xv_d[(size_t)di*48+lane];
    float e0 = eattr[(size_t)e*4];
    float e1x = eattr[(size_t)e*4+1], e1y = eattr[(size_t)e*4+2], e1z = eattr[(size_t)e*4+3];
    // out_s
    S.os[lane] = S.w[lane]*sval*e0;
    if(lane<16){
      float vd = S.v[lane*3]*e1x + S.v[lane*3+1]*e1y + S.v[lane*3+2]*e1z;
      S.os[64+lane] = S.w[144+lane]*vd*0.5773502691896258f;
    }
    // alpha + segment max
    if(lane<8){
      float a=0.f;
      #pragma unroll
      for(int c=0;c<10;c++){
        float x=S.os[lane*10+c];
        float sl = x*(0.2f + 0.8f/(1.f+expf(-x)));
        a += sl*adot[lane*10+c];
      }
      alpha[(size_t)e*8+lane]=a;
      unsigned u=__float_as_uint(a);
      u = (u&0x80000000u) ? ~u : (u|0x80000000u);
      atomicMax(&amax_u[(size_t)di*8+lane], u);
    }
    // value row (f16): layout [h*46 + c], c<10 -> a_feat, else out_v
    _Float16* vrow = value + (size_t)e*VROW;
    for(int j=lane;j<VROW;j+=64){
      int hh=j/46, c=j-hh*46;
      float val;
      if(c<10){ val = S.os[hh*10+c]; }
      else{
        int mm=c-10; int q=mm/3; int d=mm-q*3; int r=hh*12+q;
        float e1d = (d==0)?e1x:((d==1)?e1y:e1z);
        if(r<64){ val = S.w[64+r]*S.s[r]*e1d; }
        else if(r<80){ int k=r-64; val = S.w[128+k]*S.v[k*3+d]*e0; }
        else{
          int k=r-80;
          float ax=S.v[k*3], ay=S.v[k*3+1], az=S.v[k*3+2];
          float cx = ay*e1z - az*e1y;
          float cy = az*e1x - ax*e1z;
          float cz = ax*e1y - ay*e1x;
          val = S.w[160+k]*((d==0)?cx:(d==1)?cy:cz)*0.7071067811865475f;
        }
      }
      vrow[j] = (_Float16)val;
    }
  }
}

// ---------- K3: softmax (exp + denominator) ----------
__global__ void k_soft(const int* __restrict__ edst, float* __restrict__ alpha,
                       const unsigned* __restrict__ amax_u, float* __restrict__ den, int tot)
{
  int i = blockIdx.x*256 + threadIdx.x;
  if(i>=tot) return;
  int e=i>>3, hh=i&7;
  int d_=edst[e];
  unsigned u = amax_u[(size_t)d_*8+hh];
  float mx = (u&0x80000000u) ? __uint_as_float(u^0x80000000u) : __uint_as_float(~u);
  float ex = expf(alpha[i]-mx);
  alpha[i]=ex;
  atomicAdd(&den[(size_t)d_*8+hh], ex);
}

// ---------- K4: weighted scatter-add ----------
__global__ void k_agg(const int* __restrict__ edst, const float* __restrict__ ex,
                      const _Float16* __restrict__ value, float* __restrict__ agg, int tot)
{
  int i = blockIdx.x*256 + threadIdx.x;
  if(i>=tot) return;
  int e = i/VROW; int j = i - e*VROW;
  int hh = j/46;
  float v = (float)value[i];
  float w = ex[(size_t)e*8+hh];
  atomicAdd(&agg[(size_t)edst[e]*VROW+j], w*v);
}

// ---------- K5: normalize + output projections ----------
__global__ __launch_bounds__(256) void k_proj(
  const float* __restrict__ agg, const float* __restrict__ den,
  const float* __restrict__ pws, const float* __restrict__ pbs,
  const float* __restrict__ pwv, float* __restrict__ out, int N)
{
  __shared__ float sWs[80*64];   // 20 KB
  __shared__ float sWv[96*16];   // 6 KB
  __shared__ float sA[4][VROW];
  int t=threadIdx.x, wid=t>>6, lane=t&63;
  for(int i=t;i<80*64;i+=256) sWs[i]=pws[i];
  for(int i=t;i<96*16;i+=256) sWv[i]=pwv[i];
  __syncthreads();
  int n = blockIdx.x*4 + wid;
  if(n>=N) return;
  const float* arow = agg + (size_t)n*VROW;
  float* A = sA[wid];
  for(int j=lane;j<VROW;j+=64){
    int hh=j/46;
    A[j] = arow[j] / (den[(size_t)n*8+hh] + 1e-9f);
  }
  // out_sf[lane] = sum_{i<80} s_agg[i]*pws[i][lane] + pbs[lane]
  float o1 = pbs[lane];
  #pragma unroll 8
  for(int i=0;i<80;i++){
    int hh=i/10, c=i-hh*10;
    o1 += A[hh*46+c]*sWs[i*64+lane];
  }
  out[(size_t)n*112+lane]=o1;
  // out_vf: lanes<48: e=lane/3, d=lane%3
  if(lane<48){
    int ee=lane/3, d=lane-ee*3; float o2=0.f;
    #pragma unroll 8
    for(int c=0;c<96;c++){
      int hh=c/12, q=c-hh*12;
      o2 += A[hh*46+10+q*3+d]*sWv[c*16+ee];
    }
    out[(size_t)n*112+64+lane]=o2;
  }
}

extern "C" void kernel_launch(void* const* d_in, const int* in_sizes, int n_in,
                              void* d_out, int out_size, void* d_ws, size_t ws_size,
                              hipStream_t stream)
{
  const int N = in_sizes[0]/112;
  const int E = in_sizes[1];
  const float* ni    = (const float*)d_in[0];
  const int*   esrc  = (const int*)d_in[1];
  const int*   edst  = (const int*)d_in[2];
  const float* eattr = (const float*)d_in[3];
  const float* escal = (const float*)d_in[4];
  const float* wss   = (const float*)d_in[5];
  const float* wsv   = (const float*)d_in[6];
  const float* wds   = (const float*)d_in[7];
  const float* wdv   = (const float*)d_in[8];
  const float* rw1   = (const float*)d_in[9];
  const float* rb1   = (const float*)d_in[10];
  const float* rw2   = (const float*)d_in[11];
  const float* rb2   = (const float*)d_in[12];
  const float* adot  = (const float*)d_in[13];
  const float* pws   = (const float*)d_in[14];
  const float* pbs   = (const float*)d_in[15];
  const float* pwv   = (const float*)d_in[16];
  float* out = (float*)d_out;

  char* ws = (char*)d_ws;
  size_t off = 0;
  auto alloc = [&](size_t bytes)->void*{
    void* p = ws + off;
    off = (off + bytes + 255) & ~(size_t)255;
    return p;
  };
  float*    xs_s  = (float*)   alloc((size_t)N*64*4);
  float*    xs_d  = (float*)   alloc((size_t)N*64*4);
  float*    xv_s  = (float*)   alloc((size_t)N*48*4);
  float*    xv_d  = (float*)   alloc((size_t)N*48*4);
  float*    alpha = (float*)   alloc((size_t)E*8*4);
  unsigned* amax  = (unsigned*)alloc((size_t)N*8*4);
  float*    den   = (float*)   alloc((size_t)N*8*4);
  float*    agg   = (float*)   alloc((size_t)N*VROW*4);
  _Float16* value = (_Float16*)alloc((size_t)E*VROW*2);

  // zero accumulators (every call: graph replays must start clean)
  hipMemsetAsync(den, 0, (size_t)N*8*4, stream);
  hipMemsetAsync(agg, 0, (size_t)N*VROW*4, stream);
  k_init_amax<<<(N*8+255)/256, 256, 0, stream>>>(amax, N*8);

  k_node<<<(N+3)/4, 256, 0, stream>>>(ni, wss, wsv, wds, wdv, xs_s, xs_d, xv_s, xv_d, N);

  k_edge<<<(E+15)/16, 256, 0, stream>>>(esrc, edst, eattr, escal,
        rw1, rb1, rw2, rb2, adot, xs_s, xs_d, xv_s, xv_d, value, alpha, amax, E);

  k_soft<<<(E*8+255)/256, 256, 0, stream>>>(edst, alpha, amax, den, E*8);

  {
    int tot = E*VROW;   // 147.2M < 2^31
    k_agg<<<(tot+255)/256, 256, 0, stream>>>(edst, alpha, value, agg, tot);
  }

  k_proj<<<(N+3)/4, 256, 0, stream>>>(agg, den, pws, pbs, pwv, out, N);
}

// Round 2
// 1699.799 us; speedup vs baseline: 1.5846x; 1.5846x over previous
//
#include <hip/hip_runtime.h>

#define NS 64
#define NV 16
#define NH 8
#define VROW 368   // 8 heads * 46

typedef __attribute__((ext_vector_type(8))) short bf16x8;
typedef __attribute__((ext_vector_type(4))) float f32x4;

__device__ inline ushort f2bf(float f){
  unsigned u = __float_as_uint(f);
  unsigned r = ((u >> 16) & 1u) + 0x7FFFu;
  return (ushort)((u + r) >> 16);
}
__device__ inline float bf2f(ushort h){ return __uint_as_float(((unsigned)h) << 16); }

// ---------- K0: init segment-max to ordered(-inf) ----------
__global__ void k_init_amax(unsigned* __restrict__ amax, int n){
  int i = blockIdx.x*256 + threadIdx.x;
  if(i<n) amax[i] = 0x007FFFFFu;
}

// ---------- K1: node transforms (64 nodes / block) ----------
__global__ __launch_bounds__(256) void k_node(
  const float* __restrict__ ni,
  const float* __restrict__ wss, const float* __restrict__ wsv,
  const float* __restrict__ wds, const float* __restrict__ wdv,
  float* __restrict__ xs_s, float* __restrict__ xs_d,
  float* __restrict__ xv_s, float* __restrict__ xv_d, int N)
{
  __shared__ float sW0[64*64], sW1[64*64];
  __shared__ float sV0[256], sV1[256];
  __shared__ float sRow[4][112];
  int t = threadIdx.x, wid = t>>6, lane = t&63;
  for(int i=t;i<4096;i+=256){ sW0[i]=wss[i]; sW1[i]=wds[i]; }
  if(t<256){ sV0[t]=wsv[t]; sV1[t]=wdv[t]; }
  __syncthreads();
  for(int itn=0; itn<16; ++itn){
    int node = blockIdx.x*64 + itn*4 + wid;
    if(node>=N) continue;
    const float* row = ni + (size_t)node*112;
    if(lane<56) ((float2*)sRow[wid])[lane] = ((const float2*)row)[lane];
    float* r = sRow[wid];
    float a0=0.f, a1=0.f;
    #pragma unroll 8
    for(int k=0;k<64;k++){ float x=r[k]; a0+=x*sW0[k*64+lane]; a1+=x*sW1[k*64+lane]; }
    xs_s[(size_t)node*64+lane]=a0; xs_d[(size_t)node*64+lane]=a1;
    if(lane<48){
      int e_=lane/3, d_=lane-e_*3; float b0=0.f, b1=0.f;
      #pragma unroll
      for(int c=0;c<16;c++){ float x=r[64+c*3+d_]; b0+=x*sV0[c*16+e_]; b1+=x*sV1[c*16+e_]; }
      xv_s[(size_t)node*48+lane]=b0; xv_d[(size_t)node*48+lane]=b1;
    }
  }
}

// ---------- K2: MFMA radial MLP + geometric features ----------
// Tile = 32 edges; 8 tiles per block (256 edges). 4 waves.
struct __align__(16) EdgeSmem {
  ushort w1t[64*136];          // W1^T [n][k] bf16, stride 136
  ushort w2t[176*72];          // W2^T [n][k] bf16, stride 72
  union U { ushort es[32*136]; float mid[32*68]; } em;  // es tile / mid (aliased)
  ushort ht[32*72];            // h tile bf16, stride 72
  _Float16 ws[32*192];         // w output f16, stride 192
  float scr_os[4][80];
  float scr_s[4][64];
  float scr_v[4][48];
  float b1s[64];
  float b2s[176];
  float adots[80];
  uchar4 tbl[368];
};

__global__ __launch_bounds__(256) void k_edge(
  const int* __restrict__ esrc, const int* __restrict__ edst,
  const float* __restrict__ eattr, const float* __restrict__ escal,
  const float* __restrict__ w1, const float* __restrict__ b1,
  const float* __restrict__ w2, const float* __restrict__ b2,
  const float* __restrict__ adot,
  const float* __restrict__ xs_s, const float* __restrict__ xs_d,
  const float* __restrict__ xv_s, const float* __restrict__ xv_d,
  _Float16* __restrict__ value, float* __restrict__ alpha,
  unsigned* __restrict__ amax_u, int E)
{
  __shared__ EdgeSmem sm;
  int t = threadIdx.x, wid = t>>6, lane = t&63;

  // ---- one-time staging ----
  for(int i=t;i<128*64;i+=256){ int k=i>>6, n=i&63; sm.w1t[n*136+k]=f2bf(w1[i]); }
  for(int i=t;i<64*176;i+=256){ int k=i/176, n=i-k*176; sm.w2t[n*72+k]=f2bf(w2[i]); }
  if(t<64)  sm.b1s[t]=b1[t];
  if(t<176) sm.b2s[t]=b2[t];
  if(t<80)  sm.adots[t]=adot[t];
  for(int j=t;j<368;j+=256){
    int hh=j/46, c=j-hh*46, q=0, d=0;
    if(c>=10){ int mm=c-10; q=mm/3; d=mm-q*3; }
    sm.tbl[j]=make_uchar4((unsigned char)hh,(unsigned char)c,(unsigned char)q,(unsigned char)d);
  }
  __syncthreads();

  int r16 = lane&15, g = lane>>4;
  int nb = wid*16;

  for(int it=0; it<8; ++it){
    int ebase = blockIdx.x*256 + it*32;
    if(ebase >= E) continue;

    // ---- stage es tile (32 x 128 fp32 -> bf16) ----
    for(int i=t;i<1024;i+=256){
      int rr=i>>5, c4=i&31;
      int er = ebase+rr; if(er>=E) er=E-1;
      float4 v4 = *(const float4*)&escal[(size_t)er*128 + c4*4];
      ushort4 h4 = make_ushort4(f2bf(v4.x),f2bf(v4.y),f2bf(v4.z),f2bf(v4.w));
      *(ushort4*)&sm.em.es[rr*136 + c4*4] = h4;
    }
    __syncthreads();  // B1

    // ---- GEMM1: mid[32][64] = es @ W1 ----
    f32x4 acc0 = {0,0,0,0}, acc1 = {0,0,0,0};
    #pragma unroll
    for(int ks=0;ks<4;ks++){
      int koff = g*8 + ks*32;
      bf16x8 a0 = *(const bf16x8*)&sm.em.es[r16*136 + koff];
      bf16x8 a1 = *(const bf16x8*)&sm.em.es[(r16+16)*136 + koff];
      bf16x8 b  = *(const bf16x8*)&sm.w1t[(nb+r16)*136 + koff];
      acc0 = __builtin_amdgcn_mfma_f32_16x16x32_bf16(a0,b,acc0,0,0,0);
      acc1 = __builtin_amdgcn_mfma_f32_16x16x32_bf16(a1,b,acc1,0,0,0);
    }
    __syncthreads();  // B2: all waves done reading es (mid aliases it)

    {
      int col = nb + r16, rb = g*4;
      #pragma unroll
      for(int q=0;q<4;q++){
        sm.em.mid[(rb+q)*68 + col]    = acc0[q];
        sm.em.mid[(rb+q+16)*68 + col] = acc1[q];
      }
    }
    __syncthreads();  // B3

    // ---- LayerNorm + silu -> ht (bf16) ----
    {
      int rr = t>>3, sub = t&7;
      const float* mrow = &sm.em.mid[rr*68];
      float xv[8];
      *(float4*)&xv[0] = *(const float4*)&mrow[sub*8];
      *(float4*)&xv[4] = *(const float4*)&mrow[sub*8+4];
      float sum=0.f, sq=0.f;
      #pragma unroll
      for(int i=0;i<8;i++){ xv[i] += sm.b1s[sub*8+i]; sum += xv[i]; sq += xv[i]*xv[i]; }
      #pragma unroll
      for(int o=1;o<8;o<<=1){ sum += __shfl_xor(sum,o); sq += __shfl_xor(sq,o); }
      float m = sum*(1.f/64.f);
      float var = sq*(1.f/64.f) - m*m;
      float inv = rsqrtf(var + 1e-5f);
      bf16x8 hv;
      #pragma unroll
      for(int i=0;i<8;i++){
        float xn = (xv[i]-m)*inv;
        float h = xn/(1.f+__expf(-xn));
        hv[i] = (short)f2bf(h);
      }
      *(bf16x8*)&sm.ht[rr*72 + sub*8] = hv;
    }
    __syncthreads();  // B4

    // ---- GEMM2: w[32][176] = h @ W2 + b2 ----
    {
      f32x4 c2a[3], c2b[3];
      #pragma unroll
      for(int s=0;s<3;s++){ c2a[s]=(f32x4){0,0,0,0}; c2b[s]=(f32x4){0,0,0,0}; }
      #pragma unroll
      for(int ks=0;ks<2;ks++){
        int koff = g*8 + ks*32;
        bf16x8 a0 = *(const bf16x8*)&sm.ht[r16*72 + koff];
        bf16x8 a1 = *(const bf16x8*)&sm.ht[(r16+16)*72 + koff];
        #pragma unroll
        for(int s=0;s<3;s++){
          int nt = wid + s*4;
          if(nt < 11){
            bf16x8 b = *(const bf16x8*)&sm.w2t[(nt*16+r16)*72 + koff];
            c2a[s] = __builtin_amdgcn_mfma_f32_16x16x32_bf16(a0,b,c2a[s],0,0,0);
            c2b[s] = __builtin_amdgcn_mfma_f32_16x16x32_bf16(a1,b,c2b[s],0,0,0);
          }
        }
      }
      int rb = g*4;
      #pragma unroll
      for(int s=0;s<3;s++){
        int nt = wid + s*4;
        if(nt < 11){
          int col = nt*16 + r16;
          float bb = sm.b2s[col];
          #pragma unroll
          for(int q=0;q<4;q++){
            sm.ws[(rb+q)*192 + col]    = (_Float16)(c2a[s][q] + bb);
            sm.ws[(rb+q+16)*192 + col] = (_Float16)(c2b[s][q] + bb);
          }
        }
      }
    }
    __syncthreads();  // B5

    // ---- geometric phase: 8 edges per wave ----
    for(int i=0;i<8;i++){
      int el = wid*8 + i;
      int e  = ebase + el;
      if(e >= E) continue;
      const _Float16* wrow = &sm.ws[el*192];
      int si = esrc[e], di = edst[e];
      float sval = xs_s[(size_t)si*64+lane] + xs_d[(size_t)di*64+lane];
      sm.scr_s[wid][lane] = sval;
      if(lane<48) sm.scr_v[wid][lane] = xv_s[(size_t)si*48+lane] + xv_d[(size_t)di*48+lane];
      float4 ea = *(const float4*)&eattr[(size_t)e*4];
      float e0=ea.x, e1x=ea.y, e1y=ea.z, e1z=ea.w;
      float osl = (float)wrow[lane]*sval*e0;
      sm.scr_os[wid][lane] = osl;
      if(lane<16){
        float vx=sm.scr_v[wid][lane*3], vy=sm.scr_v[wid][lane*3+1], vz=sm.scr_v[wid][lane*3+2];
        float vd = vx*e1x + vy*e1y + vz*e1z;
        sm.scr_os[wid][64+lane] = (float)wrow[144+lane]*vd*0.5773502691896258f;
      }
      if(lane<8){
        float a=0.f;
        #pragma unroll
        for(int c=0;c<10;c++){
          float x = sm.scr_os[wid][lane*10+c];
          float sl = x*(0.2f + 0.8f/(1.f+__expf(-x)));
          a += sl*sm.adots[lane*10+c];
        }
        alpha[(size_t)e*8+lane]=a;
        unsigned u=__float_as_uint(a);
        u = (u&0x80000000u) ? ~u : (u|0x80000000u);
        atomicMax(&amax_u[(size_t)di*8+lane], u);
      }
      _Float16* vrow = value + (size_t)e*VROW;
      for(int j=lane;j<VROW;j+=64){
        uchar4 tb = sm.tbl[j];
        int hh=tb.x, c=tb.y;
        float val;
        if(c<10){ val = sm.scr_os[wid][hh*10+c]; }
        else{
          int q=tb.z, d=tb.w; int rr=hh*12+q;
          float e1d = (d==0)?e1x:((d==1)?e1y:e1z);
          if(rr<64){ val = (float)wrow[64+rr]*sm.scr_s[wid][rr]*e1d; }
          else if(rr<80){ int k=rr-64; val = (float)wrow[128+k]*sm.scr_v[wid][k*3+d]*e0; }
          else{
            int k=rr-80;
            float ax=sm.scr_v[wid][k*3], ay=sm.scr_v[wid][k*3+1], az=sm.scr_v[wid][k*3+2];
            float cx = ay*e1z - az*e1y;
            float cy = az*e1x - ax*e1z;
            float cz = ax*e1y - ay*e1x;
            val = (float)wrow[160+k]*((d==0)?cx:(d==1)?cy:cz)*0.7071067811865475f;
          }
        }
        vrow[j] = (_Float16)val;
      }
    }
    __syncthreads();  // B6
  }
}

// ---------- K3: softmax (exp + denominator) ----------
__global__ void k_soft(const int* __restrict__ edst, float* __restrict__ alpha,
                       const unsigned* __restrict__ amax_u, float* __restrict__ den, int tot)
{
  int i = blockIdx.x*256 + threadIdx.x;
  if(i>=tot) return;
  int e=i>>3, hh=i&7;
  int d_=edst[e];
  unsigned u = amax_u[(size_t)d_*8+hh];
  float mx = (u&0x80000000u) ? __uint_as_float(u^0x80000000u) : __uint_as_float(~u);
  float ex = __expf(alpha[i]-mx);
  alpha[i]=ex;
  atomicAdd(&den[(size_t)d_*8+hh], ex);
}

// ---------- K4: weighted scatter-add ----------
__global__ void k_agg(const int* __restrict__ edst, const float* __restrict__ ex,
                      const _Float16* __restrict__ value, float* __restrict__ agg, int tot)
{
  int i = blockIdx.x*256 + threadIdx.x;
  if(i>=tot) return;
  int e = i/VROW; int j = i - e*VROW;
  int hh = j/46;
  float v = (float)value[i];
  float w = ex[(size_t)e*8+hh];
  atomicAdd(&agg[(size_t)edst[e]*VROW+j], w*v);
}

// ---------- K5: normalize + output projections (64 nodes / block) ----------
__global__ __launch_bounds__(256) void k_proj(
  const float* __restrict__ agg, const float* __restrict__ den,
  const float* __restrict__ pws, const float* __restrict__ pbs,
  const float* __restrict__ pwv, float* __restrict__ out, int N)
{
  __shared__ float sWs[80*64];
  __shared__ float sWv[96*16];
  __shared__ float sA[4][VROW];
  int t=threadIdx.x, wid=t>>6, lane=t&63;
  for(int i=t;i<80*64;i+=256) sWs[i]=pws[i];
  for(int i=t;i<96*16;i+=256) sWv[i]=pwv[i];
  __syncthreads();
  for(int itn=0; itn<16; ++itn){
    int n = blockIdx.x*64 + itn*4 + wid;
    if(n>=N) continue;
    const float* arow = agg + (size_t)n*VROW;
    float* A = sA[wid];
    for(int j=lane;j<VROW;j+=64){
      int hh=j/46;
      A[j] = arow[j] / (den[(size_t)n*8+hh] + 1e-9f);
    }
    float o1 = pbs[lane];
    #pragma unroll 8
    for(int i=0;i<80;i++){
      int hh=i/10, c=i-hh*10;
      o1 += A[hh*46+c]*sWs[i*64+lane];
    }
    out[(size_t)n*112+lane]=o1;
    if(lane<48){
      int ee=lane/3, d=lane-ee*3; float o2=0.f;
      #pragma unroll 8
      for(int c=0;c<96;c++){
        int hh=c/12, q=c-hh*12;
        o2 += A[hh*46+10+q*3+d]*sWv[c*16+ee];
      }
      out[(size_t)n*112+64+lane]=o2;
    }
  }
}

extern "C" void kernel_launch(void* const* d_in, const int* in_sizes, int n_in,
                              void* d_out, int out_size, void* d_ws, size_t ws_size,
                              hipStream_t stream)
{
  const int N = in_sizes[0]/112;
  const int E = in_sizes[1];
  const float* ni    = (const float*)d_in[0];
  const int*   esrc  = (const int*)d_in[1];
  const int*   edst  = (const int*)d_in[2];
  const float* eattr = (const float*)d_in[3];
  const float* escal = (const float*)d_in[4];
  const float* wss   = (const float*)d_in[5];
  const float* wsv   = (const float*)d_in[6];
  const float* wds   = (const float*)d_in[7];
  const float* wdv   = (const float*)d_in[8];
  const float* rw1   = (const float*)d_in[9];
  const float* rb1   = (const float*)d_in[10];
  const float* rw2   = (const float*)d_in[11];
  const float* rb2   = (const float*)d_in[12];
  const float* adot  = (const float*)d_in[13];
  const float* pws   = (const float*)d_in[14];
  const float* pbs   = (const float*)d_in[15];
  const float* pwv   = (const float*)d_in[16];
  float* out = (float*)d_out;

  char* ws = (char*)d_ws;
  size_t off = 0;
  auto alloc = [&](size_t bytes)->void*{
    void* p = ws + off;
    off = (off + bytes + 255) & ~(size_t)255;
    return p;
  };
  float*    xs_s  = (float*)   alloc((size_t)N*64*4);
  float*    xs_d  = (float*)   alloc((size_t)N*64*4);
  float*    xv_s  = (float*)   alloc((size_t)N*48*4);
  float*    xv_d  = (float*)   alloc((size_t)N*48*4);
  float*    alpha = (float*)   alloc((size_t)E*8*4);
  unsigned* amax  = (unsigned*)alloc((size_t)N*8*4);
  float*    den   = (float*)   alloc((size_t)N*8*4);
  float*    agg   = (float*)   alloc((size_t)N*VROW*4);
  _Float16* value = (_Float16*)alloc((size_t)E*VROW*2);

  hipMemsetAsync(den, 0, (size_t)N*8*4, stream);
  hipMemsetAsync(agg, 0, (size_t)N*VROW*4, stream);
  k_init_amax<<<(N*8+255)/256, 256, 0, stream>>>(amax, N*8);

  k_node<<<(N+63)/64, 256, 0, stream>>>(ni, wss, wsv, wds, wdv, xs_s, xs_d, xv_s, xv_d, N);

  k_edge<<<(E+255)/256, 256, 0, stream>>>(esrc, edst, eattr, escal,
        rw1, rb1, rw2, rb2, adot, xs_s, xs_d, xv_s, xv_d, value, alpha, amax, E);

  k_soft<<<(E*8+255)/256, 256, 0, stream>>>(edst, alpha, amax, den, E*8);

  {
    int tot = E*VROW;
    k_agg<<<(tot+255)/256, 256, 0, stream>>>(edst, alpha, value, agg, tot);
  }

  k_proj<<<(N+63)/64, 256, 0, stream>>>(agg, den, pws, pbs, pwv, out, N);
}